// Round 9
// baseline (1113.849 us; speedup 1.0000x reference)
//
#include <hip/hip_runtime.h>

#define L_T 512
#define BATCH 1024
#define LB (L_T*BATCH)
#define NT (LB/64)

typedef short bf16x8 __attribute__((ext_vector_type(8)));
typedef float f32x4 __attribute__((ext_vector_type(4)));
typedef unsigned short u16;

#define MFMA_B16(a,b,c) __builtin_amdgcn_mfma_f32_16x16x32_bf16((a),(b),(c),0,0,0)

union U8 { unsigned u[4]; uint4 q; bf16x8 v; };

__device__ __forceinline__ short f2bs(float f){
  union{float f; unsigned u;} c; c.f=f;
  unsigned r = (c.u + 0x7FFFu + ((c.u>>16)&1u)) >> 16;
  return (short)r;
}

__device__ __forceinline__ unsigned cvtpk(float lo, float hi){
  unsigned d;
  asm("v_cvt_pk_bf16_f32 %0, %1, %2" : "=v"(d) : "v"(lo), "v"(hi));
  return d;
}

__device__ __forceinline__ float fsig(float x){
  return __builtin_amdgcn_rcpf(1.0f + __expf(-x));
}
__device__ __forceinline__ float ftanh(float x){
  return 1.0f - 2.0f*__builtin_amdgcn_rcpf(1.0f + __expf(2.0f*x));
}

__device__ __forceinline__ void store8(u16* d, float4 a, float4 b){
  bf16x8 v;
  v[0]=f2bs(a.x); v[1]=f2bs(a.y); v[2]=f2bs(a.z); v[3]=f2bs(a.w);
  v[4]=f2bs(b.x); v[5]=f2bs(b.y); v[6]=f2bs(b.z); v[7]=f2bs(b.w);
  *(bf16x8*)d = v;
}

__device__ __forceinline__ bf16x8 bfrag_f32(const float* p){
  float4 a = *(const float4*)p;
  float4 b = *(const float4*)(p+4);
  bf16x8 v;
  v[0]=f2bs(a.x); v[1]=f2bs(a.y); v[2]=f2bs(a.z); v[3]=f2bs(a.w);
  v[4]=f2bs(b.x); v[5]=f2bs(b.y); v[6]=f2bs(b.z); v[7]=f2bs(b.w);
  return v;
}

__device__ __forceinline__ f32x4 ldbias(const float* p){
  float4 b = *(const float4*)p;
  f32x4 r; r[0]=b.x; r[1]=b.y; r[2]=b.z; r[3]=b.w;
  return r;
}

__device__ __forceinline__ void dma16(const void* g, void* l){
  __builtin_amdgcn_global_load_lds(
      (const __attribute__((address_space(1))) void*)g,
      (__attribute__((address_space(3))) void*)l, 16, 0, 0);
}

// ---------------------------------------------------------------------------
// K1: two-layer preprocess. x-branch: bf16 park (mu region) + f32 out;
// u-branch: bf16 park (ws).
// ---------------------------------------------------------------------------
__device__ __forceinline__ void pre_body(
    int bid,
    const float* __restrict__ src, const float* __restrict__ W1,
    const float* __restrict__ b1, const float* __restrict__ W2,
    const float* __restrict__ b2,
    u16* __restrict__ out_b16, float* __restrict__ out_f32)
{
  __shared__ u16 in_t[64*40];
  __shared__ u16 w1t[64*40];
  __shared__ u16 w2t[64*88];
  __shared__ u16 t1t[64*88];
  __shared__ float lb1[64], lb2[64];

  const int t = threadIdx.x;
  const size_t row0 = (size_t)bid * 64;

  {
    int r = t>>2, q = t&3;
    const float* ps = src + (row0 + r)*32 + q*8;
    store8(in_t + r*40 + q*8, *(const float4*)ps, *(const float4*)(ps+4));
    const float* pw = W1 + r*32 + q*8;
    store8(w1t + r*40 + q*8, *(const float4*)pw, *(const float4*)(pw+4));
    const float* pw2 = W2 + r*64 + q*16;
    store8(w2t + r*88 + q*16,     *(const float4*)pw2,     *(const float4*)(pw2+4));
    store8(w2t + r*88 + q*16 + 8, *(const float4*)(pw2+8), *(const float4*)(pw2+12));
    if (t < 64) lb1[t] = b1[t];
    else if (t < 128) lb2[t-64] = b2[t-64];
  }
  __syncthreads();

  const int lane = t & 63, wave = t >> 6;
  const int l15 = lane & 15, l4 = lane >> 4;
  const int rs = wave*16;

  {
    bf16x8 a = *(const bf16x8*)(in_t + (rs + l15)*40 + l4*8);
    #pragma unroll
    for (int ct = 0; ct < 4; ++ct) {
      f32x4 acc = {0.f,0.f,0.f,0.f};
      bf16x8 bw = *(const bf16x8*)(w1t + (ct*16 + l15)*40 + l4*8);
      acc = MFMA_B16(a, bw, acc);
      float bias = lb1[ct*16 + l15];
      #pragma unroll
      for (int i = 0; i < 4; ++i) {
        float v = fmaxf(acc[i] + bias, 0.f);
        t1t[(rs + l4*4 + i)*88 + ct*16 + l15] = (u16)f2bs(v);
      }
    }
  }
  __syncthreads();

  {
    bf16x8 a0 = *(const bf16x8*)(t1t + (rs + l15)*88 + l4*8);
    bf16x8 a1 = *(const bf16x8*)(t1t + (rs + l15)*88 + 32 + l4*8);
    #pragma unroll
    for (int ct = 0; ct < 4; ++ct) {
      f32x4 acc = {0.f,0.f,0.f,0.f};
      bf16x8 b0 = *(const bf16x8*)(w2t + (ct*16 + l15)*88 + l4*8);
      bf16x8 b1v = *(const bf16x8*)(w2t + (ct*16 + l15)*88 + 32 + l4*8);
      acc = MFMA_B16(a0, b0, acc);
      acc = MFMA_B16(a1, b1v, acc);
      float bias = lb2[ct*16 + l15];
      #pragma unroll
      for (int i = 0; i < 4; ++i) {
        float v = fmaxf(acc[i] + bias, 0.f);
        size_t gr = row0 + rs + l4*4 + i;
        int col = ct*16 + l15;
        out_b16[gr*64 + col] = (u16)f2bs(v);
        if (out_f32) out_f32[gr*64 + col] = v;
      }
    }
  }
}

__global__ __launch_bounds__(256) void k_pre2(
    const float* __restrict__ obs,
    const float* __restrict__ pxW1, const float* __restrict__ pxb1,
    const float* __restrict__ pxW2, const float* __restrict__ pxb2,
    u16* __restrict__ xpark, float* __restrict__ xembf32,
    const float* __restrict__ ext,
    const float* __restrict__ puW1, const float* __restrict__ pub1,
    const float* __restrict__ puW2, const float* __restrict__ pub2,
    u16* __restrict__ upark)
{
  int bid = blockIdx.x;
  if (bid < NT) pre_body(bid, obs, pxW1, pxb1, pxW2, pxb2, xpark, xembf32);
  else          pre_body(bid - NT, ext, puW1, pub1, puW2, pub2, upark, nullptr);
}

// ---------------------------------------------------------------------------
// K2: 3-role cross-block pipeline. 192 blocks x 256 thr.
//   blocks 0-63:    INF  scan (v4 structure, chunk-DMA x)
//   blocks 64-127:  MID  posterior+sample+z_emb (4-step batches)
//   blocks 128-191: GEN  scan (v4 structure, reg-prefetch u, per-step z)
// Sync: per-16-row-group flags in ws; release = vmcnt(0)+syncthreads+tid0
// threadfence+atomic store; consumers acquire-load + spin (bailout-capped).
// Parking: dseq[t] = hseq row t bytes 0..127; zemb[t] = hseq row t+1 bytes
// 128..255 (t=511 -> z511 in ws); xemb bf16 = mu region (clobber-safe by
// flag order); gen overwrites hseq rows with f32 after consumption.
// ---------------------------------------------------------------------------
__global__ __launch_bounds__(256, 1) void k_pipe(
    const u16* __restrict__ xpark,    // [LB][64] bf16 (mu region)
    const u16* __restrict__ upark,    // [LB][64] bf16 (ws)
    u16* __restrict__ z511,           // [BATCH][64] bf16 (ws)
    const float* __restrict__ eps,
    const float* __restrict__ iWih, const float* __restrict__ iWhh,
    const float* __restrict__ ibih, const float* __restrict__ ibhh,
    const float* __restrict__ gWih, const float* __restrict__ gWhh,
    const float* __restrict__ gbih, const float* __restrict__ gbhh,
    const float* __restrict__ poW1, const float* __restrict__ pob1,
    const float* __restrict__ poW2, const float* __restrict__ pob2,
    const float* __restrict__ poWmu, const float* __restrict__ pobmu,
    const float* __restrict__ poWls, const float* __restrict__ pobls,
    const float* __restrict__ pzW1, const float* __restrict__ pzb1,
    const float* __restrict__ pzW2, const float* __restrict__ pzb2,
    float* __restrict__ out_mu, float* __restrict__ out_ls,
    float* __restrict__ out_s,
    float* __restrict__ hseq, float* __restrict__ hn,
    unsigned* __restrict__ flags)     // [0..63] inf, [64..127] mid
{
  __shared__ u16 smem[21504];

  const int t = threadIdx.x;
  const int lane = t & 63, w = t >> 6;
  const int l15 = lane & 15, l4 = lane >> 4;
  const int role = blockIdx.x >> 6;
  const int ib = blockIdx.x & 63;
  const int b0 = ib * 16;
  const int kcol = w*16 + l15;
  const int c0   = w*16 + l4*4;
  u16* parkU16 = (u16*)hseq;        // rows of 128 u16

  unsigned* prog_inf = flags + ib;
  unsigned* prog_mid = flags + 64 + ib;

  if (role == 0) {
    // ================= INF =================
    u16* xchunk = smem;              // [2][8192]
    u16* ht = smem + 16384;          // [2][1152]

    bf16x8 wihf[3][2], whhf[3][2];
    #pragma unroll
    for (int g = 0; g < 3; ++g) {
      int grow = g*64 + kcol;
      #pragma unroll
      for (int kc = 0; kc < 2; ++kc) {
        wihf[g][kc] = bfrag_f32(iWih + (size_t)grow*64 + kc*32 + l4*8);
        whhf[g][kc] = bfrag_f32(iWhh + (size_t)grow*64 + kc*32 + l4*8);
      }
    }
    f32x4 bv0, bv1, bvi, bvh;
    #pragma unroll
    for (int i = 0; i < 4; ++i) {
      bv0[i] = ibih[c0+i]      + ibhh[c0+i];
      bv1[i] = ibih[64+c0+i]   + ibhh[64+c0+i];
      bvi[i] = ibih[128+c0+i];
      bvh[i] = ibhh[128+c0+i];
    }

    auto issue_chunk = [&](int chunk, int bufi){
      const size_t step0 = (size_t)chunk*8;
      u16* dst0 = xchunk + bufi*8192;
      #pragma unroll
      for (int j = 0; j < 4; ++j) {
        int o = (j*4 + w)*1024;
        int slot = o/16 + lane;
        int r_all = slot >> 3;
        int q = slot & 7;
        int slice = r_all >> 4, r = r_all & 15;
        int qs = q ^ (r & 7);
        const u16* g = xpark + ((step0 + slice)*BATCH + b0 + r)*64 + qs*8;
        dma16(g, dst0 + o/2);
      }
    };

    float h[4] = {0.f,0.f,0.f,0.f};
    f32x4 gp0, gp1, gp2;
    issue_chunk(0, 0);

    for (int c = 0; c < 64; ++c) {
      const int cb = c & 1;
      const u16* xbuf = xchunk + cb*8192;
      #pragma unroll
      for (int sp = 0; sp < 8; ++sp) {
        const int step = c*8 + sp;

        uint2 pv; pv.x = cvtpk(h[0], h[1]); pv.y = cvtpk(h[2], h[3]);
        *(uint2*)(ht + (sp&1)*1152 + l15*72 + c0) = pv;

        if (sp == 0) asm volatile("s_waitcnt vmcnt(0)" ::: "memory");
        asm volatile("s_waitcnt lgkmcnt(0)\n\ts_barrier" ::: "memory");

        const u16* htr = ht + (sp&1)*1152 + l15*72;
        bf16x8 ha0 = *(const bf16x8*)(htr + l4*8);
        bf16x8 ha1 = *(const bf16x8*)(htr + 32 + l4*8);

        f32x4 a0, a1, a2;
        if (sp == 0) {
          const u16* xb = xbuf + l15*64;
          bf16x8 xa[2];
          #pragma unroll
          for (int kc = 0; kc < 2; ++kc)
            xa[kc] = *(const bf16x8*)(xb + (((l4 + 4*kc) ^ (l15 & 7)) * 8));
          a0 = bv0; a1 = bv1; a2 = bvi;
          #pragma unroll
          for (int kc = 0; kc < 2; ++kc) {
            a0 = MFMA_B16(wihf[0][kc], xa[kc], a0);
            a1 = MFMA_B16(wihf[1][kc], xa[kc], a1);
            a2 = MFMA_B16(wihf[2][kc], xa[kc], a2);
          }
        } else {
          a0 = gp0; a1 = gp1; a2 = gp2;
        }

        if (sp == 1 && c + 1 < 64) issue_chunk(c + 1, cb ^ 1);

        f32x4 g0 = MFMA_B16(whhf[0][0], ha0, a0);
        g0       = MFMA_B16(whhf[0][1], ha1, g0);
        f32x4 g1 = MFMA_B16(whhf[1][0], ha0, a1);
        g1       = MFMA_B16(whhf[1][1], ha1, g1);
        f32x4 gn = MFMA_B16(whhf[2][0], ha0, bvh);
        gn       = MFMA_B16(whhf[2][1], ha1, gn);

        if (sp < 7) {
          const u16* xb = xbuf + (sp+1)*1024 + l15*64;
          bf16x8 xn[2];
          #pragma unroll
          for (int kc = 0; kc < 2; ++kc)
            xn[kc] = *(const bf16x8*)(xb + (((l4 + 4*kc) ^ (l15 & 7)) * 8));
          gp0 = bv0; gp1 = bv1; gp2 = bvi;
          #pragma unroll
          for (int kc = 0; kc < 2; ++kc) {
            gp0 = MFMA_B16(wihf[0][kc], xn[kc], gp0);
            gp1 = MFMA_B16(wihf[1][kc], xn[kc], gp1);
            gp2 = MFMA_B16(wihf[2][kc], xn[kc], gp2);
          }
        }

        #pragma unroll
        for (int i = 0; i < 4; ++i) {
          float r = fsig(g0[i]);
          float z = fsig(g1[i]);
          float n = ftanh(a2[i] + r*gn[i]);
          h[i] = z*(h[i] - n) + n;
        }

        uint2 dv; dv.x = cvtpk(h[0], h[1]); dv.y = cvtpk(h[2], h[3]);
        *(uint2*)(parkU16 + ((size_t)step*BATCH + b0 + l15)*128 + c0) = dv;

        if (sp == 7) {   // publish every 8 steps
          asm volatile("s_waitcnt vmcnt(0)" ::: "memory");
          __syncthreads();
          if (t == 0) {
            __threadfence();
            __hip_atomic_store(prog_inf, (unsigned)(step+1),
                               __ATOMIC_RELAXED, __HIP_MEMORY_SCOPE_AGENT);
          }
        }
      }
    }
  } else if (role == 1) {
    // ================= MID =================
    u16* t1s = smem;                  // [4][1152]
    u16* z1s = smem + 4608;           // [4][1152]
    u16* ss  = smem + 9216;           // [4][640]
    float* mulsF = (float*)(smem + 11776);  // [4][16][72] f32

    bf16x8 w1f[2], w2f[2], hf[2], z1f, z2f[2];
    #pragma unroll
    for (int kc = 0; kc < 2; ++kc) {
      w1f[kc] = bfrag_f32(poW1 + (size_t)kcol*64 + kc*32 + l4*8);
      w2f[kc] = bfrag_f32(poW2 + (size_t)kcol*64 + kc*32 + l4*8);
      z2f[kc] = bfrag_f32(pzW2 + (size_t)kcol*64 + kc*32 + l4*8);
    }
    const float* headW = (w < 2) ? poWmu : poWls;
    const int hrow = (w&1)*16 + l15;
    const int ch0  = (w&1)*16 + l4*4;
    #pragma unroll
    for (int kc = 0; kc < 2; ++kc)
      hf[kc] = bfrag_f32(headW + (size_t)hrow*64 + kc*32 + l4*8);
    z1f = bfrag_f32(pzW1 + (size_t)kcol*32 + l4*8);

    f32x4 b1v = ldbias(pob1 + c0), b2v = ldbias(pob2 + c0);
    f32x4 bhv = ldbias(((w < 2) ? pobmu : pobls) + ch0);
    f32x4 bz1 = ldbias(pzb1 + c0), bz2 = ldbias(pzb2 + c0);

    unsigned avail = 0;
    for (int T0 = 0; T0 < L_T; T0 += 4) {
      unsigned need = (unsigned)(T0 + 4);
      long long spins = 0;
      while (avail < need) {
        avail = __hip_atomic_load(prog_inf, __ATOMIC_ACQUIRE, __HIP_MEMORY_SCOPE_AGENT);
        if (avail < need) { __builtin_amdgcn_s_sleep(8); if (++spins > 50000000LL) break; }
      }

      // stage1: t1 = relu(W1 d + b1) * sig(W2 d + b2)
      bf16x8 df[4][2];
      #pragma unroll
      for (int j = 0; j < 4; ++j) {
        const u16* dp = parkU16 + ((size_t)(T0+j)*BATCH + b0 + l15)*128;
        df[j][0] = *(const bf16x8*)(dp + l4*8);
        df[j][1] = *(const bf16x8*)(dp + 32 + l4*8);
      }
      #pragma unroll
      for (int j = 0; j < 4; ++j) {
        f32x4 c1 = b1v, c2 = b2v;
        c1 = MFMA_B16(w1f[0], df[j][0], c1); c1 = MFMA_B16(w1f[1], df[j][1], c1);
        c2 = MFMA_B16(w2f[0], df[j][0], c2); c2 = MFMA_B16(w2f[1], df[j][1], c2);
        float tv[4];
        #pragma unroll
        for (int i = 0; i < 4; ++i) tv[i] = fmaxf(c1[i], 0.f) * fsig(c2[i]);
        uint2 pv; pv.x = cvtpk(tv[0], tv[1]); pv.y = cvtpk(tv[2], tv[3]);
        *(uint2*)(t1s + j*1152 + l15*72 + c0) = pv;
      }
      __syncthreads();

      // stage2a: heads -> global f32 + LDS f32
      #pragma unroll
      for (int j = 0; j < 4; ++j) {
        bf16x8 tb0 = *(const bf16x8*)(t1s + j*1152 + l15*72 + l4*8);
        bf16x8 tb1 = *(const bf16x8*)(t1s + j*1152 + l15*72 + 32 + l4*8);
        f32x4 ch = bhv;
        ch = MFMA_B16(hf[0], tb0, ch); ch = MFMA_B16(hf[1], tb1, ch);
        size_t R = (size_t)(T0+j)*BATCH + b0 + l15;
        float4 hv; hv.x=ch[0]; hv.y=ch[1]; hv.z=ch[2]; hv.w=ch[3];
        float* gdst = ((w < 2) ? out_mu : out_ls) + R*32 + ch0;
        *(float4*)gdst = hv;
        *(float4*)(mulsF + (size_t)(j*16 + l15)*72 + ((w < 2) ? 0 : 36) + ch0) = hv;
      }
      __syncthreads();

      // stage2b: sample (waves 0,1)
      if (w < 2) {
        #pragma unroll
        for (int j = 0; j < 4; ++j) {
          size_t R = (size_t)(T0+j)*BATCH + b0 + l15;
          float4 mu4 = *(const float4*)(mulsF + (size_t)(j*16 + l15)*72 + ch0);
          float4 ls4 = *(const float4*)(mulsF + (size_t)(j*16 + l15)*72 + 36 + ch0);
          float4 e4  = *(const float4*)(eps + R*32 + ch0);
          float sv[4];
          sv[0] = mu4.x + __expf(0.5f*ls4.x)*e4.x;
          sv[1] = mu4.y + __expf(0.5f*ls4.y)*e4.y;
          sv[2] = mu4.z + __expf(0.5f*ls4.z)*e4.z;
          sv[3] = mu4.w + __expf(0.5f*ls4.w)*e4.w;
          float4 so; so.x=sv[0]; so.y=sv[1]; so.z=sv[2]; so.w=sv[3];
          *(float4*)(out_s + R*32 + ch0) = so;
          uint2 pv; pv.x = cvtpk(sv[0], sv[1]); pv.y = cvtpk(sv[2], sv[3]);
          *(uint2*)(ss + j*640 + l15*40 + ch0) = pv;
        }
      }
      __syncthreads();

      // stage3: z1 = relu(zW1 s + zb1)
      #pragma unroll
      for (int j = 0; j < 4; ++j) {
        bf16x8 sb = *(const bf16x8*)(ss + j*640 + l15*40 + l4*8);
        f32x4 a = bz1;
        a = MFMA_B16(z1f, sb, a);
        float zv[4];
        #pragma unroll
        for (int i = 0; i < 4; ++i) zv[i] = fmaxf(a[i], 0.f);
        uint2 pv; pv.x = cvtpk(zv[0], zv[1]); pv.y = cvtpk(zv[2], zv[3]);
        *(uint2*)(z1s + j*1152 + l15*72 + c0) = pv;
      }
      __syncthreads();

      // stage4: zemb = relu(zW2 z1 + zb2) -> park
      #pragma unroll
      for (int j = 0; j < 4; ++j) {
        bf16x8 zb0 = *(const bf16x8*)(z1s + j*1152 + l15*72 + l4*8);
        bf16x8 zb1 = *(const bf16x8*)(z1s + j*1152 + l15*72 + 32 + l4*8);
        f32x4 a = bz2;
        a = MFMA_B16(z2f[0], zb0, a); a = MFMA_B16(z2f[1], zb1, a);
        float zv[4];
        #pragma unroll
        for (int i = 0; i < 4; ++i) zv[i] = fmaxf(a[i], 0.f);
        uint2 pv; pv.x = cvtpk(zv[0], zv[1]); pv.y = cvtpk(zv[2], zv[3]);
        int tt = T0 + j;
        u16* zdst = (tt < L_T-1)
            ? parkU16 + ((size_t)(tt+1)*BATCH + b0 + l15)*128 + 64 + c0
            : z511 + (size_t)(b0 + l15)*64 + c0;
        *(uint2*)zdst = pv;
      }

      asm volatile("s_waitcnt vmcnt(0)" ::: "memory");
      __syncthreads();   // also WAR barrier for ring reuse
      if (t == 0) {
        __threadfence();
        __hip_atomic_store(prog_mid, (unsigned)(T0+4),
                           __ATOMIC_RELAXED, __HIP_MEMORY_SCOPE_AGENT);
      }
    }
  } else {
    // ================= GEN =================
    u16* ht = smem;                   // [2][1152]

    bf16x8 wihf[3][4], whhf[3][2];
    #pragma unroll
    for (int g = 0; g < 3; ++g) {
      int grow = g*64 + kcol;
      #pragma unroll
      for (int kc = 0; kc < 4; ++kc)
        wihf[g][kc] = bfrag_f32(gWih + (size_t)grow*128 + kc*32 + l4*8);
      #pragma unroll
      for (int kc = 0; kc < 2; ++kc)
        whhf[g][kc] = bfrag_f32(gWhh + (size_t)grow*64 + kc*32 + l4*8);
    }
    f32x4 bv0, bv1, bvi, bvh;
    #pragma unroll
    for (int i = 0; i < 4; ++i) {
      bv0[i] = gbih[c0+i]      + gbhh[c0+i];
      bv1[i] = gbih[64+c0+i]   + gbhh[64+c0+i];
      bvi[i] = gbih[128+c0+i];
      bvh[i] = gbhh[128+c0+i];
    }

    const u16* ubase = upark + ((size_t)b0 + l15)*64 + l4*8;
    const size_t ustep = (size_t)BATCH*64;
    bf16x8 uA0 = *(const bf16x8*)(ubase);
    bf16x8 uA1 = *(const bf16x8*)(ubase + 32);
    bf16x8 uB0 = *(const bf16x8*)(ubase + ustep);
    bf16x8 uB1 = *(const bf16x8*)(ubase + ustep + 32);

    float h[4] = {0.f,0.f,0.f,0.f};
    unsigned avail = 0;

    for (int s = 0; s < L_T; ++s) {
      unsigned need = (unsigned)(s + 1);
      long long spins = 0;
      while (avail < need) {
        avail = __hip_atomic_load(prog_mid, __ATOMIC_ACQUIRE, __HIP_MEMORY_SCOPE_AGENT);
        if (avail < need) { __builtin_amdgcn_s_sleep(8); if (++spins > 50000000LL) break; }
      }

      // z fragments for this step
      const u16* zp = (s < L_T-1)
          ? parkU16 + ((size_t)(s+1)*BATCH + b0 + l15)*128 + 64
          : z511 + (size_t)(b0 + l15)*64;
      bf16x8 z0 = *(const bf16x8*)(zp + l4*8);
      bf16x8 z1v = *(const bf16x8*)(zp + 32 + l4*8);

      // publish h
      uint2 pv; pv.x = cvtpk(h[0], h[1]); pv.y = cvtpk(h[2], h[3]);
      *(uint2*)(ht + (s&1)*1152 + l15*72 + c0) = pv;
      asm volatile("s_waitcnt lgkmcnt(0)\n\ts_barrier" ::: "memory");

      // pre-update state -> hseq[s] (row s: dseq consumed by mid; zemb lives in row s+1)
      float4 hv; hv.x=h[0]; hv.y=h[1]; hv.z=h[2]; hv.w=h[3];
      *(float4*)(hseq + ((size_t)s*BATCH + b0 + l15)*64 + c0) = hv;

      bf16x8 u0, u1;
      if ((s & 1) == 0) { u0 = uA0; u1 = uA1; }
      else              { u0 = uB0; u1 = uB1; }
      {
        size_t sn = (size_t)((s + 2 < L_T) ? s + 2 : L_T - 1);
        const u16* q = ubase + sn*ustep;
        if ((s & 1) == 0) { uA0 = *(const bf16x8*)q; uA1 = *(const bf16x8*)(q + 32); }
        else              { uB0 = *(const bf16x8*)q; uB1 = *(const bf16x8*)(q + 32); }
      }

      const u16* htr = ht + (s&1)*1152 + l15*72;
      bf16x8 ha0 = *(const bf16x8*)(htr + l4*8);
      bf16x8 ha1 = *(const bf16x8*)(htr + 32 + l4*8);

      f32x4 g0 = bv0, g1 = bv1, a2 = bvi;
      g0 = MFMA_B16(wihf[0][0], z0, g0);  g0 = MFMA_B16(wihf[0][1], z1v, g0);
      g0 = MFMA_B16(wihf[0][2], u0, g0);  g0 = MFMA_B16(wihf[0][3], u1, g0);
      g1 = MFMA_B16(wihf[1][0], z0, g1);  g1 = MFMA_B16(wihf[1][1], z1v, g1);
      g1 = MFMA_B16(wihf[1][2], u0, g1);  g1 = MFMA_B16(wihf[1][3], u1, g1);
      a2 = MFMA_B16(wihf[2][0], z0, a2);  a2 = MFMA_B16(wihf[2][1], z1v, a2);
      a2 = MFMA_B16(wihf[2][2], u0, a2);  a2 = MFMA_B16(wihf[2][3], u1, a2);

      g0 = MFMA_B16(whhf[0][0], ha0, g0); g0 = MFMA_B16(whhf[0][1], ha1, g0);
      g1 = MFMA_B16(whhf[1][0], ha0, g1); g1 = MFMA_B16(whhf[1][1], ha1, g1);
      f32x4 gn = MFMA_B16(whhf[2][0], ha0, bvh);
      gn       = MFMA_B16(whhf[2][1], ha1, gn);

      #pragma unroll
      for (int i = 0; i < 4; ++i) {
        float r = fsig(g0[i]);
        float z = fsig(g1[i]);
        float n = ftanh(a2[i] + r*gn[i]);
        h[i] = z*(h[i] - n) + n;
      }
    }

    float4 hv; hv.x=h[0]; hv.y=h[1]; hv.z=h[2]; hv.w=h[3];
    *(float4*)(hn + ((size_t)b0 + l15)*64 + c0) = hv;
  }
}

// ---------------------------------------------------------------------------

extern "C" void kernel_launch(void* const* d_in, const int* in_sizes, int n_in,
                              void* d_out, int out_size, void* d_ws, size_t ws_size,
                              hipStream_t stream) {
  const float* ext  = (const float*)d_in[0];
  const float* obs  = (const float*)d_in[1];
  const float* eps  = (const float*)d_in[2];
  const float* puW1 = (const float*)d_in[3];  const float* pub1 = (const float*)d_in[4];
  const float* puW2 = (const float*)d_in[5];  const float* pub2 = (const float*)d_in[6];
  const float* pxW1 = (const float*)d_in[7];  const float* pxb1 = (const float*)d_in[8];
  const float* pxW2 = (const float*)d_in[9];  const float* pxb2 = (const float*)d_in[10];
  const float* pzW1 = (const float*)d_in[11]; const float* pzb1 = (const float*)d_in[12];
  const float* pzW2 = (const float*)d_in[13]; const float* pzb2 = (const float*)d_in[14];
  const float* poW1 = (const float*)d_in[15]; const float* pob1 = (const float*)d_in[16];
  const float* poW2 = (const float*)d_in[17]; const float* pob2 = (const float*)d_in[18];
  const float* poWmu= (const float*)d_in[19]; const float* pobmu= (const float*)d_in[20];
  const float* poWls= (const float*)d_in[21]; const float* pobls= (const float*)d_in[22];
  const float* iWih = (const float*)d_in[23]; const float* iWhh = (const float*)d_in[24];
  const float* ibih = (const float*)d_in[25]; const float* ibhh = (const float*)d_in[26];
  const float* gWih = (const float*)d_in[27]; const float* gWhh = (const float*)d_in[28];
  const float* gbih = (const float*)d_in[29]; const float* gbhh = (const float*)d_in[30];

  float* out = (float*)d_out;
  const size_t OFF_MU   = 0;
  const size_t OFF_LS   = (size_t)LB*32;
  const size_t OFF_S    = (size_t)LB*64;
  const size_t OFF_HSEQ = (size_t)LB*96;
  const size_t OFF_XEMB = (size_t)LB*96 + (size_t)LB*64;
  const size_t OFF_HN   = OFF_XEMB + (size_t)LB*64;

  unsigned* flags = (unsigned*)d_ws;                           // 4 KB
  u16* upark = (u16*)((char*)d_ws + 4096);                     // [LB][64]
  u16* z511  = (u16*)((char*)d_ws + 4096 + (size_t)LB*128);    // [BATCH][64]
  u16* xpark = (u16*)out;                                      // mu region [LB][64]

  hipMemsetAsync(d_ws, 0, 4096, stream);

  // 1. x_emb (bf16 park in mu region + f32 out) and u_emb (bf16 park in ws)
  k_pre2<<<2*NT, 256, 0, stream>>>(obs, pxW1, pxb1, pxW2, pxb2, xpark, out + OFF_XEMB,
                                   ext, puW1, pub1, puW2, pub2, upark);
  // 2. 3-role pipeline: inf scan || posterior+sample+z_emb || gen scan
  k_pipe<<<192, 256, 0, stream>>>(xpark, upark, z511, eps,
                                  iWih, iWhh, ibih, ibhh,
                                  gWih, gWhh, gbih, gbhh,
                                  poW1, pob1, poW2, pob2,
                                  poWmu, pobmu, poWls, pobls,
                                  pzW1, pzb1, pzW2, pzb2,
                                  out + OFF_MU, out + OFF_LS, out + OFF_S,
                                  out + OFF_HSEQ, out + OFF_HN, flags);
}